// Round 8
// baseline (777.770 us; speedup 1.0000x reference)
//
#include <hip/hip_runtime.h>
#include <stdint.h>
#include <stddef.h>

#define N_NODES 20000
#define N_EDGES 320000

typedef unsigned short u16;
typedef __attribute__((ext_vector_type(8))) short bf16x8;
typedef __attribute__((ext_vector_type(8))) unsigned short u16x8;
typedef __attribute__((ext_vector_type(4))) float f32x4;

__device__ __forceinline__ float bf2f(u16 u) {
    union { unsigned int i; float f; } v; v.i = ((unsigned int)u) << 16; return v.f;
}
__device__ __forceinline__ u16 f2bf(float f) {
    union { float f; unsigned int i; } v; v.f = f;
    unsigned int x = v.i;
    unsigned int r = x + 0x7fffu + ((x >> 16) & 1u);
    return (u16)(r >> 16);
}
__device__ __forceinline__ int clampi(int v, int lo, int hi) {
    return v < lo ? lo : (v > hi ? hi : v);
}
__device__ __forceinline__ float ld1(const void* p, size_t i, int f32) {
    return f32 ? ((const float*)p)[i] : bf2f(((const u16*)p)[i]);
}

__global__ void marker_kernel(u16* out, u16 code) { out[threadIdx.x] = code; }

// dtype sniff + sentinel. diag[0]=sentinel, diag[1]=fp32 flag, diag[2]=const 0
__global__ void detect_kernel(const void* feat, int* diag) {
    int lane = threadIdx.x;
    int weird = 0;
    const u16* p = (const u16*)feat;
    for (int i = lane; i < 512; i += 64) {
        float v = bf2f(p[i]);
        float a = fabsf(v);
        if (!(a <= 1e4f) || (a != 0.f && a < 1e-6f)) weird++;
    }
#pragma unroll
    for (int off = 32; off > 0; off >>= 1) weird += __shfl_xor(weird, off, 64);
    if (lane == 0) { diag[0] = 123456; diag[1] = (weird > 51) ? 1 : 0; diag[2] = 0; }
}

// rpe collapse: out[p*4+h] = sum_d Wrpe[p][h*64+d]; out[12+h] = sum_d brpe[h*64+d]
__global__ void rpe_sums_kernel(const void* __restrict__ Wrpe, const void* __restrict__ brpe,
                                float* __restrict__ out, const int* __restrict__ dflag) {
    int f32 = dflag[0];
    int t = threadIdx.x;
    if (t < 12) {
        int p = t >> 2, h = t & 3;
        float s = 0.f;
        for (int d = 0; d < 64; ++d) s += ld1(Wrpe, p * 256 + h * 64 + d, f32);
        out[t] = s;
    } else if (t < 16) {
        int h = t - 12;
        float s = 0.f;
        for (int d = 0; d < 64; ++d) s += ld1(brpe, h * 64 + d, f32);
        out[12 + h] = s;
    }
}

// proj[n*4+h] = sum_p coord[n,p] * rpe_sums[p*4+h]
__global__ __launch_bounds__(256) void coordproj_kernel(const void* __restrict__ coord,
                                                        const int* __restrict__ dflag,
                                                        const float* __restrict__ rs,
                                                        float* __restrict__ proj, int n) {
    int i = blockIdx.x * 256 + threadIdx.x;
    if (i >= n * 4) return;
    int f32 = dflag[0];
    int node = i >> 2, h = i & 3;
    float s = ld1(coord, (size_t)node * 3 + 0, f32) * rs[0 * 4 + h]
            + ld1(coord, (size_t)node * 3 + 1, f32) * rs[1 * 4 + h]
            + ld1(coord, (size_t)node * 3 + 2, f32) * rs[2 * 4 + h];
    proj[i] = s;
}

// Wt[n*K + k] = bf16(W[k*N + n])  (weight transpose + convert)
__global__ __launch_bounds__(256) void transpose_w_kernel(const void* __restrict__ W,
                                                          const int* __restrict__ dflag,
                                                          u16* __restrict__ Wt, int K, int N) {
    int f32 = dflag[0];
    int i = blockIdx.x * 256 + threadIdx.x;
    if (i >= K * N) return;
    int n = i / K, k = i - n * K;
    Wt[i] = f2bf(ld1(W, (size_t)k * N + n, f32));
}

// ---------------------------------------------------------------- CSR build
__global__ __launch_bounds__(256) void count_kernel(
        const int* __restrict__ g0, const int* __restrict__ g1,
        const int* __restrict__ g2, const int* __restrict__ g3,
        int* __restrict__ deg) {
    int idx = blockIdx.x * blockDim.x + threadIdx.x;
    if (idx >= 4 * N_EDGES) return;
    int gi = idx / N_EDGES, e = idx - gi * N_EDGES;
    const int* g = (gi == 0) ? g0 : (gi == 1) ? g1 : (gi == 2) ? g2 : g3;
    int dst = clampi(g[e], 0, N_NODES - 1);
    atomicAdd(&deg[gi * N_NODES + dst], 1);
}

__global__ __launch_bounds__(256) void scan_kernel(int* __restrict__ cur,
                                                   int* __restrict__ rowptr) {
    int g = blockIdx.x;
    int tid = threadIdx.x;
    __shared__ int buf[256];
    int* deg = cur + g * N_NODES;
    int* rp  = rowptr + g * (N_NODES + 1);
    const int CH = (N_NODES + 255) / 256;
    int lo = tid * CH;
    int hi = lo + CH; if (hi > N_NODES) hi = N_NODES;
    int s = 0;
    for (int i = lo; i < hi; ++i) s += deg[i];
    buf[tid] = s;
    __syncthreads();
    for (int off = 1; off < 256; off <<= 1) {
        int x = (tid >= off) ? buf[tid - off] : 0;
        __syncthreads();
        buf[tid] += x;
        __syncthreads();
    }
    int run = (tid == 0) ? 0 : buf[tid - 1];
    for (int i = lo; i < hi; ++i) {
        int v = deg[i];
        rp[i]  = run;
        deg[i] = run;
        run += v;
    }
    if (tid == 255) rp[N_NODES] = buf[255];
}

// col entries are u16 (src < 20000 < 65536): 2.56 MB total -> L2-resident,
// kills the 14x partial-line writeback amplification seen with 4B entries.
__global__ __launch_bounds__(256) void fill_kernel(
        const int* __restrict__ g0, const int* __restrict__ g1,
        const int* __restrict__ g2, const int* __restrict__ g3,
        int* __restrict__ cur, u16* __restrict__ col) {
    int idx = blockIdx.x * blockDim.x + threadIdx.x;
    if (idx >= 4 * N_EDGES) return;
    int gi = idx / N_EDGES, e = idx - gi * N_EDGES;
    const int* g = (gi == 0) ? g0 : (gi == 1) ? g1 : (gi == 2) ? g2 : g3;
    int dst = clampi(g[e], 0, N_NODES - 1);
    int src = clampi(g[N_EDGES + e], 0, N_NODES - 1);
    int pos = atomicAdd(&cur[gi * N_NODES + dst], 1);
    if (pos >= 0 && pos < N_EDGES)
        col[gi * N_EDGES + pos] = (u16)src;
}

// ---------------------------------------------------------------- MFMA GEMM
// C[M,N] = A[M,K] @ Bt[N,K]^T + bias.  128x128 tile, BK=32, 4 waves (2x2 of 64x64).
__global__ __launch_bounds__(256) void gemm_mfma(
        const void* __restrict__ A, int lda, const int* __restrict__ aflag,
        const u16* __restrict__ Bt,
        const void* __restrict__ bias, size_t biasoff, const int* __restrict__ bflag,
        void* __restrict__ C, size_t coff, int ldc, const int* __restrict__ cflag,
        int M, int N, int K) {
    __shared__ __align__(16) u16 As[128 * 40];
    __shared__ __align__(16) u16 Bs[128 * 40];
    const int f32a = aflag[0], f32b = bflag[0], f32c = cflag[0];
    const int t = threadIdx.x;
    const int lane = t & 63, wv = t >> 6;
    const int wm = (wv >> 1) * 64, wn = (wv & 1) * 64;
    const int m0 = blockIdx.y * 128, n0 = blockIdx.x * 128;
    const int l15 = lane & 15, lq = lane >> 4;

    f32x4 acc[4][4];
#pragma unroll
    for (int i = 0; i < 4; ++i)
#pragma unroll
        for (int j = 0; j < 4; ++j) acc[i][j] = (f32x4){0.f, 0.f, 0.f, 0.f};

    const int sr = t >> 1, skc = (t & 1) * 16;

    for (int k0 = 0; k0 < K; k0 += 32) {
        __syncthreads();
        {
            __align__(16) u16 tmp[16];
            int gm = m0 + sr;
            if (gm < M) {
                if (f32a) {
                    const float* ap = (const float*)A + (size_t)gm * lda + k0 + skc;
#pragma unroll
                    for (int i = 0; i < 16; i += 4) {
                        float4 u = *(const float4*)(ap + i);
                        tmp[i] = f2bf(u.x); tmp[i + 1] = f2bf(u.y);
                        tmp[i + 2] = f2bf(u.z); tmp[i + 3] = f2bf(u.w);
                    }
                } else {
                    const u16* ap = (const u16*)A + (size_t)gm * lda + k0 + skc;
                    *(u16x8*)&tmp[0] = *(const u16x8*)ap;
                    *(u16x8*)&tmp[8] = *(const u16x8*)(ap + 8);
                }
            } else {
#pragma unroll
                for (int i = 0; i < 16; ++i) tmp[i] = 0;
            }
            *(u16x8*)&As[sr * 40 + skc] = *(u16x8*)&tmp[0];
            *(u16x8*)&As[sr * 40 + skc + 8] = *(u16x8*)&tmp[8];
        }
        {
            const u16* bp = Bt + (size_t)(n0 + sr) * K + k0 + skc;
            u16x8 b0 = *(const u16x8*)bp;
            u16x8 b1 = *(const u16x8*)(bp + 8);
            *(u16x8*)&Bs[sr * 40 + skc] = b0;
            *(u16x8*)&Bs[sr * 40 + skc + 8] = b1;
        }
        __syncthreads();
        bf16x8 af[4], bfr[4];
#pragma unroll
        for (int mt = 0; mt < 4; ++mt)
            af[mt] = *(const bf16x8*)&As[(wm + mt * 16 + l15) * 40 + lq * 8];
#pragma unroll
        for (int nt = 0; nt < 4; ++nt)
            bfr[nt] = *(const bf16x8*)&Bs[(wn + nt * 16 + l15) * 40 + lq * 8];
#pragma unroll
        for (int mt = 0; mt < 4; ++mt)
#pragma unroll
            for (int nt = 0; nt < 4; ++nt)
                acc[mt][nt] = __builtin_amdgcn_mfma_f32_16x16x32_bf16(af[mt], bfr[nt], acc[mt][nt], 0, 0, 0);
    }
#pragma unroll
    for (int mt = 0; mt < 4; ++mt) {
#pragma unroll
        for (int nt = 0; nt < 4; ++nt) {
            int gn = n0 + wn + nt * 16 + l15;
            float bb = ld1(bias, biasoff + gn, f32b);
#pragma unroll
            for (int r = 0; r < 4; ++r) {
                int gm = m0 + wm + mt * 16 + lq * 4 + r;
                if (gm < M) {
                    float v = acc[mt][nt][r] + bb;
                    size_t ic = coff + (size_t)gm * ldc + gn;
                    if (f32c) ((float*)C)[ic] = v;
                    else      ((u16*)C)[ic] = f2bf(v);
                }
            }
        }
    }
}

// ---------------------------------------------------------------- edge attention v4
// wave per dst node; lane = h*16+j; lane owns d = j*4..j*4+3 of head h.
// 8x edge unroll: 16 independent gathers in flight, one softmax rescale per chunk.
__global__ __launch_bounds__(256) void attn4_kernel(
        const u16* __restrict__ Q, const u16* __restrict__ Kp, const u16* __restrict__ Vp,
        const int* __restrict__ rowptr, const u16* __restrict__ col,
        const float* __restrict__ projN, const float* __restrict__ projS,
        const float* __restrict__ rb, int use_rpe,
        u16* __restrict__ outp) {
    int lane = threadIdx.x & 63;
    int node = blockIdx.x * 4 + (threadIdx.x >> 6);
    if (node >= N_NODES) return;
    int h = lane >> 4;
    int off = h * 64 + (lane & 15) * 4;

    ushort4 qu = *(const ushort4*)(Q + (size_t)node * 768 + off);
    float q0 = bf2f(qu.x), q1 = bf2f(qu.y), q2 = bf2f(qu.z), q3 = bf2f(qu.w);
    float base = use_rpe ? (projN[node * 4 + h] + rb[h]) : 0.f;

    float m = -1e30f, l = 0.f, a0 = 0.f, a1 = 0.f, a2 = 0.f, a3 = 0.f;
    int e0 = rowptr[node], e1 = rowptr[node + 1];
    e0 = clampi(e0, 0, N_EDGES);
    e1 = clampi(e1, e0, N_EDGES);
    int e = e0;
    for (; e + 8 <= e1; e += 8) {
        int s[8];
#pragma unroll
        for (int i = 0; i < 8; ++i) s[i] = col[e + i];
        ushort4 kv[8], vv[8];
#pragma unroll
        for (int i = 0; i < 8; ++i) kv[i] = *(const ushort4*)(Kp + (size_t)s[i] * 768 + off);
#pragma unroll
        for (int i = 0; i < 8; ++i) vv[i] = *(const ushort4*)(Vp + (size_t)s[i] * 768 + off);
        float tt[8];
#pragma unroll
        for (int i = 0; i < 8; ++i)
            tt[i] = q0 * bf2f(kv[i].x) + q1 * bf2f(kv[i].y) + q2 * bf2f(kv[i].z) + q3 * bf2f(kv[i].w);
#pragma unroll
        for (int sh = 1; sh <= 8; sh <<= 1)
#pragma unroll
            for (int i = 0; i < 8; ++i) tt[i] += __shfl_xor(tt[i], sh, 64);
        if (use_rpe) {
#pragma unroll
            for (int i = 0; i < 8; ++i) tt[i] += base - projS[s[i] * 4 + h];
        }
        float mx = m;
#pragma unroll
        for (int i = 0; i < 8; ++i) mx = fmaxf(mx, tt[i]);
        float sc = __expf(m - mx);
        float p[8];
#pragma unroll
        for (int i = 0; i < 8; ++i) p[i] = __expf(tt[i] - mx);
        float ps = 0.f;
#pragma unroll
        for (int i = 0; i < 8; ++i) ps += p[i];
        l = l * sc + ps;
        float b0 = 0.f, b1 = 0.f, b2 = 0.f, b3 = 0.f;
#pragma unroll
        for (int i = 0; i < 8; ++i) {
            b0 += p[i] * bf2f(vv[i].x);
            b1 += p[i] * bf2f(vv[i].y);
            b2 += p[i] * bf2f(vv[i].z);
            b3 += p[i] * bf2f(vv[i].w);
        }
        a0 = a0 * sc + b0; a1 = a1 * sc + b1; a2 = a2 * sc + b2; a3 = a3 * sc + b3;
        m = mx;
    }
    for (; e < e1; ++e) {
        int src = col[e];
        ushort4 ku = *(const ushort4*)(Kp + (size_t)src * 768 + off);
        ushort4 vu = *(const ushort4*)(Vp + (size_t)src * 768 + off);
        float tv = q0 * bf2f(ku.x) + q1 * bf2f(ku.y) + q2 * bf2f(ku.z) + q3 * bf2f(ku.w);
        tv += __shfl_xor(tv, 1, 64);
        tv += __shfl_xor(tv, 2, 64);
        tv += __shfl_xor(tv, 4, 64);
        tv += __shfl_xor(tv, 8, 64);
        if (use_rpe) tv += base - projS[src * 4 + h];
        float mn = fmaxf(m, tv);
        float sc = __expf(m - mn), p = __expf(tv - mn);
        l = l * sc + p;
        a0 = a0 * sc + p * bf2f(vu.x);
        a1 = a1 * sc + p * bf2f(vu.y);
        a2 = a2 * sc + p * bf2f(vu.z);
        a3 = a3 * sc + p * bf2f(vu.w);
        m = mn;
    }
    float inv = l > 0.f ? 1.f / l : 0.f;
    ushort4 o;
    o.x = f2bf(a0 * inv); o.y = f2bf(a1 * inv); o.z = f2bf(a2 * inv); o.w = f2bf(a3 * inv);
    *(ushort4*)(outp + (size_t)node * 512 + off) = o;
}

// ---------------------------------------------------------------- launch
extern "C" void kernel_launch(void* const* d_in, const int* in_sizes, int n_in,
                              void* d_out, int out_size, void* d_ws, size_t ws_size,
                              hipStream_t stream) {
    const void* feat1  = d_in[0];
    const void* coord1 = d_in[1];
    const void* feat2  = d_in[2];
    const void* coord2 = d_in[3];
    const void* Wqkv1  = d_in[4];
    const void* bqkv1  = d_in[5];
    const void* Wqkv2  = d_in[6];
    const void* bqkv2  = d_in[7];
    const void* Wproj1 = d_in[8];
    const void* bproj1 = d_in[9];
    const void* Wproj2 = d_in[10];
    const void* bproj2 = d_in[11];
    const void* Wrpe   = d_in[12];
    const void* brpe   = d_in[13];
    const int* graph1  = (const int*)d_in[14];
    const int* graph2  = (const int*)d_in[15];
    const int* graph12 = (const int*)d_in[16];
    const int* graph21 = (const int*)d_in[17];
    u16* out = (u16*)d_out;

    {   // layout assertion
        static const int expect[18] = {
            N_NODES * 256, N_NODES * 3, N_NODES * 256, N_NODES * 3,
            256 * 1536, 1536, 256 * 1536, 1536,
            512 * 256, 256, 512 * 256, 256,
            3 * 256, 256,
            2 * N_EDGES, 2 * N_EDGES, 2 * N_EDGES, 2 * N_EDGES };
        bool ok = (n_in == 18) && (out_size == 2 * N_NODES * 256);
        if (ok) for (int i = 0; i < 18; ++i) if (in_sizes[i] != expect[i]) ok = false;
        if (!ok) { marker_kernel<<<1, 16, 0, stream>>>(out, 0x4496 /*~1200*/); return; }
    }

    char* w = (char*)d_ws;
    size_t off = 0;
    auto alloc = [&](size_t bytes) { void* p = w + off; off += (bytes + 255) & ~(size_t)255; return p; };
    u16* T       = (u16*)alloc((size_t)N_NODES * 768 * 2);
    u16* cat     = (u16*)alloc((size_t)N_NODES * 512 * 2);
    int* rowptr  = (int*)alloc(4ull * (N_NODES + 1) * 4);
    int* cur     = (int*)alloc(4ull * N_NODES * 4);
    u16* col     = (u16*)alloc(4ull * N_EDGES * 2);
    float* rpe_s = (float*)alloc(64);
    int* diag    = (int*)alloc(256);
    float* proj1 = (float*)alloc((size_t)N_NODES * 4 * 4);
    float* proj2 = (float*)alloc((size_t)N_NODES * 4 * 4);
    u16* Wqkv1t  = (u16*)alloc((size_t)1536 * 256 * 2);
    u16* Wqkv2t  = (u16*)alloc((size_t)1536 * 256 * 2);
    u16* Wproj1t = (u16*)alloc((size_t)256 * 512 * 2);
    u16* Wproj2t = (u16*)alloc((size_t)256 * 512 * 2);
    if (off > ws_size) {
        marker_kernel<<<1, 16, 0, stream>>>(out, 0x447A /*~1000*/);
        return;
    }
    const int* dF = diag + 1;
    const int* dZ = diag + 2;

    const int NP1 = N_NODES + 1;
    hipMemsetAsync(cur, 0, 4ull * N_NODES * 4, stream);
    hipMemsetAsync(diag, 0, 256, stream);

    detect_kernel<<<1, 64, 0, stream>>>(feat1, diag);
    rpe_sums_kernel<<<1, 64, 0, stream>>>(Wrpe, brpe, rpe_s, dF);
    coordproj_kernel<<<(N_NODES * 4 + 255) / 256, 256, 0, stream>>>(coord1, dF, rpe_s, proj1, N_NODES);
    coordproj_kernel<<<(N_NODES * 4 + 255) / 256, 256, 0, stream>>>(coord2, dF, rpe_s, proj2, N_NODES);
    transpose_w_kernel<<<(1536 * 256 + 255) / 256, 256, 0, stream>>>(Wqkv1, dF, Wqkv1t, 256, 1536);
    transpose_w_kernel<<<(1536 * 256 + 255) / 256, 256, 0, stream>>>(Wqkv2, dF, Wqkv2t, 256, 1536);
    transpose_w_kernel<<<(256 * 512 + 255) / 256, 256, 0, stream>>>(Wproj1, dF, Wproj1t, 512, 256);
    transpose_w_kernel<<<(256 * 512 + 255) / 256, 256, 0, stream>>>(Wproj2, dF, Wproj2t, 512, 256);

    count_kernel<<<(4 * N_EDGES + 255) / 256, 256, 0, stream>>>(graph1, graph2, graph12, graph21, cur);
    scan_kernel<<<4, 256, 0, stream>>>(cur, rowptr);
    fill_kernel<<<(4 * N_EDGES + 255) / 256, 256, 0, stream>>>(graph1, graph2, graph12, graph21, cur, col);

    const dim3 blk(256);
    const int GY = (N_NODES + 127) / 128;
    const int AG = (N_NODES + 3) / 4;

    // ---- set1 self: T = feat1 @ Wqkv1[:,0:768]
    gemm_mfma<<<dim3(6, GY), blk, 0, stream>>>(feat1, 256, dF, Wqkv1t + 0 * 256,
                                               bqkv1, 0, dF, T, 0, 768, dZ, N_NODES, 768, 256);
    attn4_kernel<<<AG, blk, 0, stream>>>(T, T + 256, T + 512, rowptr + 0 * NP1, col + 0 * (size_t)N_EDGES,
                                         proj1, proj1, rpe_s + 12, 1, cat + 0);
    // ---- cross 1<-2: {q12, k21, v21}
    gemm_mfma<<<dim3(2, GY), blk, 0, stream>>>(feat1, 256, dF, Wqkv1t + (size_t)768 * 256,
                                               bqkv1, 768, dF, T, 0, 768, dZ, N_NODES, 256, 256);
    gemm_mfma<<<dim3(4, GY), blk, 0, stream>>>(feat2, 256, dF, Wqkv2t + (size_t)256 * 256,
                                               bqkv2, 256, dF, T, 256, 768, dZ, N_NODES, 512, 256);
    attn4_kernel<<<AG, blk, 0, stream>>>(T, T + 256, T + 512, rowptr + 3 * NP1, col + 3 * (size_t)N_EDGES,
                                         nullptr, nullptr, rpe_s + 12, 0, cat + 256);
    // ---- out1 = cat @ Wproj1 + bproj1
    gemm_mfma<<<dim3(2, GY), blk, 0, stream>>>(cat, 512, dZ, Wproj1t,
                                               bproj1, 0, dF, out, 0, 256, dF, N_NODES, 256, 512);

    // ---- set2 self: T = feat2 @ Wqkv2[:,768:1536]
    gemm_mfma<<<dim3(6, GY), blk, 0, stream>>>(feat2, 256, dF, Wqkv2t + (size_t)768 * 256,
                                               bqkv2, 768, dF, T, 0, 768, dZ, N_NODES, 768, 256);
    attn4_kernel<<<AG, blk, 0, stream>>>(T, T + 256, T + 512, rowptr + 1 * NP1, col + 1 * (size_t)N_EDGES,
                                         proj2, proj2, rpe_s + 12, 1, cat + 0);
    // ---- cross 2<-1: {q21, k12, v12}
    gemm_mfma<<<dim3(2, GY), blk, 0, stream>>>(feat2, 256, dF, Wqkv2t + 0,
                                               bqkv2, 0, dF, T, 0, 768, dZ, N_NODES, 256, 256);
    gemm_mfma<<<dim3(4, GY), blk, 0, stream>>>(feat1, 256, dF, Wqkv1t + (size_t)1024 * 256,
                                               bqkv1, 1024, dF, T, 256, 768, dZ, N_NODES, 512, 256);
    attn4_kernel<<<AG, blk, 0, stream>>>(T, T + 256, T + 512, rowptr + 2 * NP1, col + 2 * (size_t)N_EDGES,
                                         nullptr, nullptr, rpe_s + 12, 0, cat + 256);
    // ---- out2 = cat @ Wproj2 + bproj2
    gemm_mfma<<<dim3(2, GY), blk, 0, stream>>>(cat, 512, dZ, Wproj2t,
                                               bproj2, 0, dF, out, (size_t)N_NODES * 256, 256, dF,
                                               N_NODES, 256, 512);
}